// Round 1
// baseline (926.369 us; speedup 1.0000x reference)
//
#include <hip/hip_runtime.h>

#define HH 512
#define WW 512
#define HW 262144          // 512*512
#define NPIX 1048576       // 4*512*512
#define NPIXF 1048576.0f

__device__ __forceinline__ float leaky(float v) { return v > 0.f ? v : 0.01f * v; }

// ---------------------------------------------------------------------------
// Mode pooling: quantize to 17 levels, 11x11 sliding-window histogram mode.
// Block: 256 threads = 8 rows x 32 col-segments (8 px each). LDS tile 18x266.
// Histogram: 17 bins packed 8b each into three u64 registers.
// ---------------------------------------------------------------------------
__global__ __launch_bounds__(256) void mode_kernel(const float* __restrict__ x,
                                                   unsigned char* __restrict__ modeq) {
    __shared__ unsigned char q[18 * 276];   // stride 276 (odd dword count) vs bank conflicts
    const int plane = blockIdx.z;           // b*3 + cin
    const int tc0 = blockIdx.x * 256;
    const int tr0 = blockIdx.y * 8;
    const float* xp = x + (size_t)plane * HW;
    for (int idx = threadIdx.x; idx < 18 * 266; idx += 256) {
        int r = idx / 266;
        int cc = idx - r * 266;
        int gr = tr0 + r - 5; gr = gr < 0 ? -gr : (gr > 511 ? 1022 - gr : gr);
        int gc = tc0 + cc - 5; gc = gc < 0 ? -gc : (gc > 511 ? 1022 - gc : gc);
        float v = rintf(xp[gr * WW + gc] * 15.9375f);   // 255/16, round-half-even
        v = fminf(fmaxf(v, 0.f), 16.f);
        q[r * 276 + cc] = (unsigned char)(int)v;
    }
    __syncthreads();
    const int seg = threadIdx.x & 31;
    const int row = threadIdx.x >> 5;
    const int col0 = seg * 8;
    unsigned long long h0 = 0, h1 = 0, h2c = 0;   // bins 0-7, 8-15, 16
    #pragma unroll
    for (int u = 0; u < 11; ++u) {
        const unsigned char* qr = &q[(row + u) * 276 + col0];
        #pragma unroll
        for (int v = 0; v < 11; ++v) {
            int val = qr[v];
            unsigned long long inc = 1ull << ((val & 7) * 8);
            h0 += (val < 8) ? inc : 0;
            h1 += (val >= 8 && val < 16) ? inc : 0;
            h2c += (unsigned long long)(val >> 4);
        }
    }
    unsigned long long res = 0;
    #pragma unroll
    for (int p = 0; p < 8; ++p) {
        int best = 0;
        unsigned bc = (unsigned)(h0 & 0xFF);
        #pragma unroll
        for (int vv = 1; vv < 17; ++vv) {
            unsigned long long wsel = (vv < 8) ? h0 : ((vv < 16) ? h1 : h2c);
            unsigned cnt = (unsigned)((wsel >> ((vv & 7) * 8)) & 0xFF);
            if (cnt > bc) { bc = cnt; best = vv; }   // strict >: first max wins (argmax)
        }
        res |= (unsigned long long)best << (p * 8);
        if (p < 7) {
            #pragma unroll
            for (int u = 0; u < 11; ++u) {
                const unsigned char* qr = &q[(row + u) * 276 + col0 + p];
                int vr = qr[0];     // leaving column
                unsigned long long ir = 1ull << ((vr & 7) * 8);
                h0 -= (vr < 8) ? ir : 0;
                h1 -= (vr >= 8 && vr < 16) ? ir : 0;
                h2c -= (unsigned long long)(vr >> 4);
                int va = qr[11];    // entering column
                unsigned long long ia = 1ull << ((va & 7) * 8);
                h0 += (va < 8) ? ia : 0;
                h1 += (va >= 8 && va < 16) ? ia : 0;
                h2c += (unsigned long long)(va >> 4);
            }
        }
    }
    size_t obase = (size_t)plane * HW + (size_t)(tr0 + row) * WW + tc0 + col0;
    *(unsigned long long*)(modeq + obase) = res;   // 8B-aligned packed store
}

// ---------------------------------------------------------------------------
// Channel-mix stats pass. lane = channel (c = lane&31); each (wave,half) slot
// walks pixels grid-stride. apply_bn1==0: stats of h2.  ==1: stats of
// t = leaky(bn1(h2)).
// ---------------------------------------------------------------------------
__global__ __launch_bounds__(256) void stats_kernel(const unsigned char* __restrict__ modeq,
                                                    const float* __restrict__ w1,
                                                    const float* __restrict__ b1,
                                                    const float* __restrict__ w2,
                                                    const float* __restrict__ b2,
                                                    const float* __restrict__ p1,
                                                    int apply_bn1,
                                                    float* __restrict__ stats) {
    const int lane = threadIdx.x & 63;
    const int c = lane & 31;
    float w2r[6];
    #pragma unroll
    for (int k = 0; k < 6; ++k) w2r[k] = w2[c * 6 + k];
    const float b2c = b2[c];
    float w1r[18], b1r[6];
    #pragma unroll
    for (int k = 0; k < 18; ++k) w1r[k] = w1[k];
    #pragma unroll
    for (int o = 0; o < 6; ++o) b1r[o] = b1[o];
    float a1 = 0.f, c1 = 0.f;
    if (apply_bn1) { a1 = p1[c]; c1 = p1[32 + c]; }
    int slot = blockIdx.x * 8 + (threadIdx.x >> 6) * 2 + (lane >> 5);
    int stride = gridDim.x * 8;
    float sm = 0.f, sq = 0.f;
    for (int p = slot; p < NPIX; p += stride) {
        int b = p >> 18;
        int hw = p & (HW - 1);
        const unsigned char* mp = modeq + (size_t)b * 3 * HW + hw;
        float xm0 = mp[0] * 0.0625f, xm1 = mp[HW] * 0.0625f, xm2 = mp[2 * HW] * 0.0625f;
        float t1[6];
        #pragma unroll
        for (int o = 0; o < 6; ++o)
            t1[o] = leaky(xm0 * w1r[o * 3] + xm1 * w1r[o * 3 + 1] + xm2 * w1r[o * 3 + 2] + b1r[o]);
        float h2 = b2c;
        #pragma unroll
        for (int k = 0; k < 6; ++k) h2 += w2r[k] * t1[k];
        float v = apply_bn1 ? leaky(h2 * a1 + c1) : h2;
        sm += v;
        sq += v * v;
    }
    sm += __shfl_xor(sm, 32);
    sq += __shfl_xor(sq, 32);
    __shared__ float rs[4][32], rq[4][32];
    int wave = threadIdx.x >> 6;
    if ((lane >> 5) == 0) { rs[wave][c] = sm; rq[wave][c] = sq; }
    __syncthreads();
    if (threadIdx.x < 32) {
        int cc = threadIdx.x;
        atomicAdd(&stats[cc], rs[0][cc] + rs[1][cc] + rs[2][cc] + rs[3][cc]);
        atomicAdd(&stats[32 + cc], rq[0][cc] + rq[1][cc] + rq[2][cc] + rq[3][cc]);
    }
}

__global__ void fin1_kernel(const float* __restrict__ stats, const float* __restrict__ g,
                            const float* __restrict__ bb, float* __restrict__ p1) {
    int c = threadIdx.x;
    float m = stats[c] / NPIXF;
    float v = stats[32 + c] / NPIXF - m * m;
    float a = g[c] * rsqrtf(v + 1e-5f);
    p1[c] = a;
    p1[32 + c] = bb[c] - m * a;
}

__global__ void fin2_kernel(const float* __restrict__ stats, const float* __restrict__ w3,
                            const float* __restrict__ b3, const float* __restrict__ g,
                            const float* __restrict__ bb, float* __restrict__ p2) {
    int c = threadIdx.x;
    float mt = stats[c] / NPIXF;
    float vt = stats[32 + c] / NPIXF - mt * mt;
    float m2 = w3[c] * mt + b3[c];            // BN2 input = t*w3+b3 (affine of t)
    float v2 = w3[c] * w3[c] * vt;
    float a = g[c] * rsqrtf(v2 + 1e-5f);
    p2[c] = a;
    p2[32 + c] = bb[c] - m2 * a;
}

// ---------------------------------------------------------------------------
// Level-1 downsample fused with the whole prepare chain (h never materialized;
// stride-3 3x3 windows are disjoint so each h pixel is used exactly once).
// One thread per (b, i, j), all 32 channels in registers.
// ---------------------------------------------------------------------------
__global__ __launch_bounds__(64) void d1_kernel(const unsigned char* __restrict__ modeq,
                                                const float* __restrict__ w1,
                                                const float* __restrict__ b1,
                                                const float* __restrict__ w2,
                                                const float* __restrict__ b2,
                                                const float* __restrict__ w3,
                                                const float* __restrict__ b3,
                                                const float* __restrict__ p1,
                                                const float* __restrict__ p2,
                                                const float* __restrict__ kd,
                                                float* __restrict__ d1) {
    int j = blockIdx.x * 64 + threadIdx.x;
    if (j >= 171) return;
    int i = blockIdx.y;
    int b = blockIdx.z;
    float acc[32];
    #pragma unroll
    for (int c = 0; c < 32; ++c) acc[c] = 0.f;
    const unsigned char* mp = modeq + (size_t)b * 3 * HW;
    #pragma unroll
    for (int u = 0; u < 3; ++u) {
        int r = 3 * i - 1 + u;
        if (r < 0 || r > 511) continue;
        #pragma unroll
        for (int v = 0; v < 3; ++v) {
            int col = 3 * j - 1 + v;
            if (col < 0 || col > 511) continue;
            int off = r * WW + col;
            float xm0 = mp[off] * 0.0625f, xm1 = mp[off + HW] * 0.0625f, xm2 = mp[off + 2 * HW] * 0.0625f;
            float t1[6];
            #pragma unroll
            for (int o = 0; o < 6; ++o)
                t1[o] = leaky(xm0 * w1[o * 3] + xm1 * w1[o * 3 + 1] + xm2 * w1[o * 3 + 2] + b1[o]);
            #pragma unroll
            for (int c = 0; c < 32; ++c) {
                float h2 = b2[c];
                #pragma unroll
                for (int k = 0; k < 6; ++k) h2 += w2[c * 6 + k] * t1[k];
                float t = leaky(h2 * p1[c] + p1[32 + c]);
                float uu = t * w3[c] + b3[c];
                float hv = leaky(uu * p2[c] + p2[32 + c]);
                acc[c] += hv * kd[c * 9 + u * 3 + v];
            }
        }
    }
    size_t base = ((size_t)(b * 32) * 171 + i) * 171 + j;
    #pragma unroll
    for (int c = 0; c < 32; ++c) d1[base + (size_t)c * 29241] = acc[c];
}

// Generic depthwise 3x3 stride-3 pad-1 downsample for levels 2..6.
__global__ __launch_bounds__(256) void down_kernel(const float* __restrict__ in,
                                                   float* __restrict__ out,
                                                   const float* __restrict__ kd,
                                                   int sin, int sout, int total) {
    int idx = blockIdx.x * 256 + threadIdx.x;
    if (idx >= total) return;
    int j = idx % sout;
    int t = idx / sout;
    int i = t % sout;
    int bc = t / sout;
    int c = bc & 31;
    const float* ip = in + (size_t)bc * sin * sin;
    float acc = 0.f;
    #pragma unroll
    for (int u = 0; u < 3; ++u) {
        int r = 3 * i - 1 + u;
        if (r < 0 || r >= sin) continue;
        #pragma unroll
        for (int v = 0; v < 3; ++v) {
            int cc = 3 * j - 1 + v;
            if (cc < 0 || cc >= sin) continue;
            acc += ip[r * sin + cc] * kd[c * 9 + u * 3 + v];
        }
    }
    out[idx] = acc;
}

// Weighted per-channel stats over one pyramid level; weights = nearest-upsample
// replication counts, so these equal stats over the upsampled [4,32,512,512].
__global__ __launch_bounds__(256) void lstats_kernel(const float* __restrict__ d, int s,
                                                     float* __restrict__ stats) {
    const int lane = threadIdx.x & 63;
    const int c = lane & 31;
    int slot = blockIdx.x * 8 + (threadIdx.x >> 6) * 2 + (lane >> 5);
    int stride = gridDim.x * 8;
    int plane = s * s;
    int npix = 4 * plane;
    float sm = 0.f, sq = 0.f;
    for (int p = slot; p < npix; p += stride) {
        int b = p / plane;
        int ij = p - b * plane;
        int i = ij / s;
        int j = ij - i * s;
        float ci = (float)(((i + 1) * 512 + s - 1) / s - (i * 512 + s - 1) / s);
        float cj = (float)(((j + 1) * 512 + s - 1) / s - (j * 512 + s - 1) / s);
        float wgt = ci * cj;
        float v = d[((size_t)(b * 32 + c) * s + i) * s + j];
        sm += wgt * v;
        sq += wgt * v * v;
    }
    sm += __shfl_xor(sm, 32);
    sq += __shfl_xor(sq, 32);
    __shared__ float rs[4][32], rq[4][32];
    int wave = threadIdx.x >> 6;
    if ((lane >> 5) == 0) { rs[wave][c] = sm; rq[wave][c] = sq; }
    __syncthreads();
    if (threadIdx.x < 32) {
        int cc = threadIdx.x;
        atomicAdd(&stats[cc], rs[0][cc] + rs[1][cc] + rs[2][cc] + rs[3][cc]);
        atomicAdd(&stats[32 + cc], rq[0][cc] + rq[1][cc] + rq[2][cc] + rq[3][cc]);
    }
}

// Fold level stats + SharedConv scale + BN into per-(level,channel) affine:
// branch value = leaky(d*A + B).
__global__ void fin3_kernel(const float* __restrict__ lstats, const float* __restrict__ kw,
                            const float* __restrict__ gw, const float* __restrict__ bw,
                            const float* __restrict__ kh, const float* __restrict__ gh,
                            const float* __restrict__ bh, float* __restrict__ lp) {
    int t = threadIdx.x;
    if (t >= 192) return;
    int l = t >> 5, c = t & 31;
    float mz = lstats[l * 64 + c] / NPIXF;
    float vz = lstats[l * 64 + 32 + c] / NPIXF - mz * mz;
    float kwc = kw[c];
    float aw = gw[c] * rsqrtf(kwc * kwc * vz + 1e-5f);
    float khc = kh[c];
    float ah = gh[c] * rsqrtf(khc * khc * vz + 1e-5f);
    float* o = lp + (size_t)(l * 32 + c) * 4;
    o[0] = kwc * aw;
    o[1] = bw[c] - kwc * mz * aw;
    o[2] = khc * ah;
    o[3] = bh[c] - khc * mz * ah;
}

// Final: per (b,c,h,w) gather 6 pyramid levels, apply per-level affine+leaky,
// write both branch channels (c and c+32).
__global__ __launch_bounds__(256) void final_kernel(const float* __restrict__ d1,
                                                    const float* __restrict__ d2,
                                                    const float* __restrict__ d3,
                                                    const float* __restrict__ d4,
                                                    const float* __restrict__ d5,
                                                    const float* __restrict__ d6,
                                                    const float* __restrict__ lp,
                                                    float* __restrict__ out) {
    int idx = blockIdx.x * 256 + threadIdx.x;
    int w = idx & 511;
    int h = (idx >> 9) & 511;
    int c = (idx >> 18) & 31;
    int b = idx >> 23;
    const float* ds[6] = {d1, d2, d3, d4, d5, d6};
    const int ss[6] = {171, 57, 19, 7, 3, 1};
    float accw = 0.f, acch = 0.f;
    #pragma unroll
    for (int l = 0; l < 6; ++l) {
        int s = ss[l];
        int sh = (h * s) >> 9;
        int sw = (w * s) >> 9;
        float val = ds[l][((size_t)(b * 32 + c) * s + sh) * s + sw];
        const float* a = lp + (size_t)(l * 32 + c) * 4;
        accw += leaky(val * a[0] + a[1]);
        acch += leaky(val * a[2] + a[3]);
    }
    size_t o = (((size_t)(b * 64 + c)) << 18) + ((size_t)h << 9) + w;
    out[o] = accw;
    out[o + ((size_t)32 << 18)] = acch;
}

extern "C" void kernel_launch(void* const* d_in, const int* in_sizes, int n_in,
                              void* d_out, int out_size, void* d_ws, size_t ws_size,
                              hipStream_t stream) {
    const float* x     = (const float*)d_in[0];
    const float* w1    = (const float*)d_in[1];
    const float* b1    = (const float*)d_in[2];
    const float* w2    = (const float*)d_in[3];
    const float* b2    = (const float*)d_in[4];
    const float* bn1g  = (const float*)d_in[5];
    const float* bn1b  = (const float*)d_in[6];
    const float* w3    = (const float*)d_in[7];
    const float* b3    = (const float*)d_in[8];
    const float* bn2g  = (const float*)d_in[9];
    const float* bn2b  = (const float*)d_in[10];
    const float* kd    = (const float*)d_in[11];
    const float* kw    = (const float*)d_in[12];
    const float* bnwg  = (const float*)d_in[13];
    const float* bnwb  = (const float*)d_in[14];
    const float* kh    = (const float*)d_in[15];
    const float* bnhg  = (const float*)d_in[16];
    const float* bnhb  = (const float*)d_in[17];
    float* out = (float*)d_out;

    char* ws = (char*)d_ws;
    unsigned char* modeq = (unsigned char*)ws;            // 3,145,728 B
    float* stats1 = (float*)(ws + 3145728);               // 64 f
    float* stats2 = stats1 + 64;                          // 64 f
    float* lstats = stats2 + 64;                          // 384 f
    float* p1 = (float*)(ws + 3145728 + 2048);            // 64 f
    float* p2 = p1 + 64;                                  // 64 f
    float* lp = p2 + 64;                                  // 768 f
    float* d1 = (float*)(ws + 3151360);                   // 3,742,848 f
    float* d2 = d1 + 3742848;                             // 415,872 f
    float* d3 = d2 + 415872;                              // 46,208 f
    float* d4 = d3 + 46208;                               // 6,272 f
    float* d5 = d4 + 6272;                                // 1,152 f
    float* d6 = d5 + 1152;                                // 128 f

    hipMemsetAsync(stats1, 0, 2048, stream);   // stats1+stats2+lstats contiguous

    mode_kernel<<<dim3(2, 64, 12), 256, 0, stream>>>(x, modeq);
    stats_kernel<<<1024, 256, 0, stream>>>(modeq, w1, b1, w2, b2, nullptr, 0, stats1);
    fin1_kernel<<<1, 32, 0, stream>>>(stats1, bn1g, bn1b, p1);
    stats_kernel<<<1024, 256, 0, stream>>>(modeq, w1, b1, w2, b2, p1, 1, stats2);
    fin2_kernel<<<1, 32, 0, stream>>>(stats2, w3, b3, bn2g, bn2b, p2);

    d1_kernel<<<dim3(3, 171, 4), 64, 0, stream>>>(modeq, w1, b1, w2, b2, w3, b3, p1, p2, kd, d1);
    down_kernel<<<(415872 + 255) / 256, 256, 0, stream>>>(d1, d2, kd, 171, 57, 415872);
    down_kernel<<<(46208 + 255) / 256, 256, 0, stream>>>(d2, d3, kd, 57, 19, 46208);
    down_kernel<<<(6272 + 255) / 256, 256, 0, stream>>>(d3, d4, kd, 19, 7, 6272);
    down_kernel<<<(1152 + 255) / 256, 256, 0, stream>>>(d4, d5, kd, 7, 3, 1152);
    down_kernel<<<1, 256, 0, stream>>>(d5, d6, kd, 3, 1, 128);

    lstats_kernel<<<128, 256, 0, stream>>>(d1, 171, lstats + 0 * 64);
    lstats_kernel<<<16, 256, 0, stream>>>(d2, 57, lstats + 1 * 64);
    lstats_kernel<<<2, 256, 0, stream>>>(d3, 19, lstats + 2 * 64);
    lstats_kernel<<<1, 256, 0, stream>>>(d4, 7, lstats + 3 * 64);
    lstats_kernel<<<1, 256, 0, stream>>>(d5, 3, lstats + 4 * 64);
    lstats_kernel<<<1, 256, 0, stream>>>(d6, 1, lstats + 5 * 64);
    fin3_kernel<<<1, 192, 0, stream>>>(lstats, kw, bnwg, bnwb, kh, bnhg, bnhb, lp);

    final_kernel<<<131072, 256, 0, stream>>>(d1, d2, d3, d4, d5, d6, lp, out);
}

// Round 2
// 682.433 us; speedup vs baseline: 1.3575x; 1.3575x over previous
//
#include <hip/hip_runtime.h>

#define HH 512
#define WW 512
#define HW 262144          // 512*512
#define NPIX 1048576       // 4*512*512
#define NPIXF 1048576.0f

__device__ __forceinline__ float leaky(float v) { return v > 0.f ? v : 0.01f * v; }

__device__ __forceinline__ void hins(unsigned long long& h0, unsigned long long& h1,
                                     unsigned& c16, int val) {
    unsigned long long inc = 1ull << ((val & 7) * 8);
    h0 += (val < 8) ? inc : 0;
    h1 += (val >= 8 && val < 16) ? inc : 0;
    c16 += (unsigned)(val >> 4);
}
__device__ __forceinline__ void hrem(unsigned long long& h0, unsigned long long& h1,
                                     unsigned& c16, int val) {
    unsigned long long inc = 1ull << ((val & 7) * 8);
    h0 -= (val < 8) ? inc : 0;
    h1 -= (val >= 8 && val < 16) ? inc : 0;
    c16 -= (unsigned)(val >> 4);
}

// ---------------------------------------------------------------------------
// Mode pooling v2: shared column histograms.
// Block: 256 threads, tile 8 output rows x 256 cols. For each output row,
// column hists (11-row windows, byte-packed u64x2 + u32) are held in owner-
// thread registers, slid vertically (2 updates/row), mirrored to LDS
// (stride 5 dwords -> conflict-free). Pixel hist = sum of 11 colhists.
// Argmax via (cnt<<8)|(16-i) u32 max tree (first-hit tie-break preserved).
// ---------------------------------------------------------------------------
__global__ __launch_bounds__(256) void mode_kernel(const float* __restrict__ x,
                                                   unsigned char* __restrict__ modeq) {
    __shared__ unsigned char q[18 * 272];   // 18 rows x 266 used, stride 272
    __shared__ unsigned ch[267 * 5];        // colhist mirror, stride 5 dwords
    const int plane = blockIdx.z;           // b*3 + cin
    const int tc0 = blockIdx.x * 256;
    const int tr0 = blockIdx.y * 8;
    const float* xp = x + (size_t)plane * HW;
    for (int idx = threadIdx.x; idx < 18 * 266; idx += 256) {
        int r = idx / 266;
        int cc = idx - r * 266;
        int gr = tr0 + r - 5; gr = gr < 0 ? -gr : (gr > 511 ? 1022 - gr : gr);
        int gc = tc0 + cc - 5; gc = gc < 0 ? -gc : (gc > 511 ? 1022 - gc : gc);
        float v = rintf(xp[gr * WW + gc] * 15.9375f);   // 255/16, round-half-even
        v = fminf(fmaxf(v, 0.f), 16.f);
        q[r * 272 + cc] = (unsigned char)(int)v;
    }
    const int t = threadIdx.x;
    unsigned long long A0 = 0, A1 = 0; unsigned A2 = 0;   // colhist for column t
    unsigned long long B0 = 0, B1 = 0; unsigned B2 = 0;   // colhist for column 256+t (t<10)
    __syncthreads();
    for (int r = 0; r < 8; ++r) {
        // --- vertical colhist update (registers only; q is stable) ---
        if (r == 0) {
            #pragma unroll
            for (int v = 0; v < 11; ++v) {
                hins(A0, A1, A2, q[v * 272 + t]);
                if (t < 10) hins(B0, B1, B2, q[v * 272 + 256 + t]);
            }
        } else {
            hrem(A0, A1, A2, q[(r - 1) * 272 + t]);
            hins(A0, A1, A2, q[(r + 10) * 272 + t]);
            if (t < 10) {
                hrem(B0, B1, B2, q[(r - 1) * 272 + 256 + t]);
                hins(B0, B1, B2, q[(r + 10) * 272 + 256 + t]);
            }
        }
        __syncthreads();   // previous row's pixel phase done reading ch
        ch[t * 5 + 0] = (unsigned)A0;
        ch[t * 5 + 1] = (unsigned)(A0 >> 32);
        ch[t * 5 + 2] = (unsigned)A1;
        ch[t * 5 + 3] = (unsigned)(A1 >> 32);
        ch[t * 5 + 4] = A2;
        if (t < 10) {
            ch[(256 + t) * 5 + 0] = (unsigned)B0;
            ch[(256 + t) * 5 + 1] = (unsigned)(B0 >> 32);
            ch[(256 + t) * 5 + 2] = (unsigned)B1;
            ch[(256 + t) * 5 + 3] = (unsigned)(B1 >> 32);
            ch[(256 + t) * 5 + 4] = B2;
        }
        __syncthreads();
        // --- pixel phase: thread t = output col t of output row r ---
        unsigned long long H0 = 0, H1 = 0; unsigned C = 0;
        #pragma unroll
        for (int v = 0; v < 11; ++v) {
            const unsigned* p = &ch[(t + v) * 5];
            H0 += (unsigned long long)p[0] | ((unsigned long long)p[1] << 32);
            H1 += (unsigned long long)p[2] | ((unsigned long long)p[3] << 32);
            C += p[4];
        }
        unsigned m = 0;
        #pragma unroll
        for (int i = 0; i < 8; ++i) {
            unsigned cnt = (unsigned)(H0 >> (8 * i)) & 0xFFu;
            unsigned val = (cnt << 8) | (unsigned)(16 - i);
            m = m > val ? m : val;
        }
        #pragma unroll
        for (int i = 8; i < 16; ++i) {
            unsigned cnt = (unsigned)(H1 >> (8 * (i - 8))) & 0xFFu;
            unsigned val = (cnt << 8) | (unsigned)(16 - i);
            m = m > val ? m : val;
        }
        unsigned val16 = (C << 8);   // | (16-16)
        m = m > val16 ? m : val16;
        int k = 16 - (int)(m & 0xFFu);
        modeq[(size_t)plane * HW + (size_t)(tr0 + r) * WW + tc0 + t] = (unsigned char)k;
    }
}

// ---------------------------------------------------------------------------
// Channel-mix stats pass, u32-packed pixel loads (4 px per load set).
// lane = channel (c = lane&31); half-wave slots walk 4-px groups grid-stride.
// apply_bn1==0: stats of h2.  ==1: stats of t = leaky(bn1(h2)).
// ---------------------------------------------------------------------------
__global__ __launch_bounds__(256) void stats_kernel(const unsigned char* __restrict__ modeq,
                                                    const float* __restrict__ w1,
                                                    const float* __restrict__ b1,
                                                    const float* __restrict__ w2,
                                                    const float* __restrict__ b2,
                                                    const float* __restrict__ p1,
                                                    int apply_bn1,
                                                    float* __restrict__ stats) {
    const int lane = threadIdx.x & 63;
    const int c = lane & 31;
    float w2r[6];
    #pragma unroll
    for (int k = 0; k < 6; ++k) w2r[k] = w2[c * 6 + k];
    const float b2c = b2[c];
    float w1r[18], b1r[6];
    #pragma unroll
    for (int k = 0; k < 18; ++k) w1r[k] = w1[k];
    #pragma unroll
    for (int o = 0; o < 6; ++o) b1r[o] = b1[o];
    float a1 = 0.f, c1 = 0.f;
    if (apply_bn1) { a1 = p1[c]; c1 = p1[32 + c]; }
    int slot = blockIdx.x * 8 + (threadIdx.x >> 6) * 2 + (lane >> 5);
    int stride = gridDim.x * 8;
    float sm = 0.f, sq = 0.f;
    for (int g = slot; g < NPIX / 4; g += stride) {
        int p0 = g << 2;
        int b = p0 >> 18;
        int hw = p0 & (HW - 1);
        const unsigned char* mp = modeq + (size_t)b * 3 * HW + hw;
        unsigned u0 = *(const unsigned*)(mp);
        unsigned u1 = *(const unsigned*)(mp + HW);
        unsigned u2 = *(const unsigned*)(mp + 2 * HW);
        #pragma unroll
        for (int k = 0; k < 4; ++k) {
            float xm0 = (float)((u0 >> (8 * k)) & 0xFF) * 0.0625f;
            float xm1 = (float)((u1 >> (8 * k)) & 0xFF) * 0.0625f;
            float xm2 = (float)((u2 >> (8 * k)) & 0xFF) * 0.0625f;
            float t1[6];
            #pragma unroll
            for (int o = 0; o < 6; ++o)
                t1[o] = leaky(xm0 * w1r[o * 3] + xm1 * w1r[o * 3 + 1] + xm2 * w1r[o * 3 + 2] + b1r[o]);
            float h2 = b2c;
            #pragma unroll
            for (int kk = 0; kk < 6; ++kk) h2 += w2r[kk] * t1[kk];
            float v = apply_bn1 ? leaky(h2 * a1 + c1) : h2;
            sm += v;
            sq += v * v;
        }
    }
    sm += __shfl_xor(sm, 32);
    sq += __shfl_xor(sq, 32);
    __shared__ float rs[4][32], rq[4][32];
    int wave = threadIdx.x >> 6;
    if ((lane >> 5) == 0) { rs[wave][c] = sm; rq[wave][c] = sq; }
    __syncthreads();
    if (threadIdx.x < 32) {
        int cc = threadIdx.x;
        atomicAdd(&stats[cc], rs[0][cc] + rs[1][cc] + rs[2][cc] + rs[3][cc]);
        atomicAdd(&stats[32 + cc], rq[0][cc] + rq[1][cc] + rq[2][cc] + rq[3][cc]);
    }
}

__global__ void fin1_kernel(const float* __restrict__ stats, const float* __restrict__ g,
                            const float* __restrict__ bb, float* __restrict__ p1) {
    int c = threadIdx.x;
    float m = stats[c] / NPIXF;
    float v = stats[32 + c] / NPIXF - m * m;
    float a = g[c] * rsqrtf(v + 1e-5f);
    p1[c] = a;
    p1[32 + c] = bb[c] - m * a;
}

__global__ void fin2_kernel(const float* __restrict__ stats, const float* __restrict__ w3,
                            const float* __restrict__ b3, const float* __restrict__ g,
                            const float* __restrict__ bb, float* __restrict__ p2) {
    int c = threadIdx.x;
    float mt = stats[c] / NPIXF;
    float vt = stats[32 + c] / NPIXF - mt * mt;
    float m2 = w3[c] * mt + b3[c];            // BN2 input = t*w3+b3 (affine of t)
    float v2 = w3[c] * w3[c] * vt;
    float a = g[c] * rsqrtf(v2 + 1e-5f);
    p2[c] = a;
    p2[32 + c] = bb[c] - m2 * a;
}

// ---------------------------------------------------------------------------
// Level-1 downsample fused with the whole prepare chain (h never materialized;
// stride-3 3x3 windows are disjoint so each h pixel is used exactly once).
// ---------------------------------------------------------------------------
__global__ __launch_bounds__(64) void d1_kernel(const unsigned char* __restrict__ modeq,
                                                const float* __restrict__ w1,
                                                const float* __restrict__ b1,
                                                const float* __restrict__ w2,
                                                const float* __restrict__ b2,
                                                const float* __restrict__ w3,
                                                const float* __restrict__ b3,
                                                const float* __restrict__ p1,
                                                const float* __restrict__ p2,
                                                const float* __restrict__ kd,
                                                float* __restrict__ d1) {
    int j = blockIdx.x * 64 + threadIdx.x;
    if (j >= 171) return;
    int i = blockIdx.y;
    int b = blockIdx.z;
    float acc[32];
    #pragma unroll
    for (int c = 0; c < 32; ++c) acc[c] = 0.f;
    const unsigned char* mp = modeq + (size_t)b * 3 * HW;
    #pragma unroll
    for (int u = 0; u < 3; ++u) {
        int r = 3 * i - 1 + u;
        if (r < 0 || r > 511) continue;
        #pragma unroll
        for (int v = 0; v < 3; ++v) {
            int col = 3 * j - 1 + v;
            if (col < 0 || col > 511) continue;
            int off = r * WW + col;
            float xm0 = mp[off] * 0.0625f, xm1 = mp[off + HW] * 0.0625f, xm2 = mp[off + 2 * HW] * 0.0625f;
            float t1[6];
            #pragma unroll
            for (int o = 0; o < 6; ++o)
                t1[o] = leaky(xm0 * w1[o * 3] + xm1 * w1[o * 3 + 1] + xm2 * w1[o * 3 + 2] + b1[o]);
            #pragma unroll
            for (int c = 0; c < 32; ++c) {
                float h2 = b2[c];
                #pragma unroll
                for (int k = 0; k < 6; ++k) h2 += w2[c * 6 + k] * t1[k];
                float t = leaky(h2 * p1[c] + p1[32 + c]);
                float uu = t * w3[c] + b3[c];
                float hv = leaky(uu * p2[c] + p2[32 + c]);
                acc[c] += hv * kd[c * 9 + u * 3 + v];
            }
        }
    }
    size_t base = ((size_t)(b * 32) * 171 + i) * 171 + j;
    #pragma unroll
    for (int c = 0; c < 32; ++c) d1[base + (size_t)c * 29241] = acc[c];
}

// Generic depthwise 3x3 stride-3 pad-1 downsample for levels 2..6.
__global__ __launch_bounds__(256) void down_kernel(const float* __restrict__ in,
                                                   float* __restrict__ out,
                                                   const float* __restrict__ kd,
                                                   int sin, int sout, int total) {
    int idx = blockIdx.x * 256 + threadIdx.x;
    if (idx >= total) return;
    int j = idx % sout;
    int t = idx / sout;
    int i = t % sout;
    int bc = t / sout;
    int c = bc & 31;
    const float* ip = in + (size_t)bc * sin * sin;
    float acc = 0.f;
    #pragma unroll
    for (int u = 0; u < 3; ++u) {
        int r = 3 * i - 1 + u;
        if (r < 0 || r >= sin) continue;
        #pragma unroll
        for (int v = 0; v < 3; ++v) {
            int cc = 3 * j - 1 + v;
            if (cc < 0 || cc >= sin) continue;
            acc += ip[r * sin + cc] * kd[c * 9 + u * 3 + v];
        }
    }
    out[idx] = acc;
}

// Weighted per-channel stats over one pyramid level; weights = nearest-upsample
// replication counts, so these equal stats over the upsampled [4,32,512,512].
__global__ __launch_bounds__(256) void lstats_kernel(const float* __restrict__ d, int s,
                                                     float* __restrict__ stats) {
    const int lane = threadIdx.x & 63;
    const int c = lane & 31;
    int slot = blockIdx.x * 8 + (threadIdx.x >> 6) * 2 + (lane >> 5);
    int stride = gridDim.x * 8;
    int plane = s * s;
    int npix = 4 * plane;
    float sm = 0.f, sq = 0.f;
    for (int p = slot; p < npix; p += stride) {
        int b = p / plane;
        int ij = p - b * plane;
        int i = ij / s;
        int j = ij - i * s;
        float ci = (float)(((i + 1) * 512 + s - 1) / s - (i * 512 + s - 1) / s);
        float cj = (float)(((j + 1) * 512 + s - 1) / s - (j * 512 + s - 1) / s);
        float wgt = ci * cj;
        float v = d[((size_t)(b * 32 + c) * s + i) * s + j];
        sm += wgt * v;
        sq += wgt * v * v;
    }
    sm += __shfl_xor(sm, 32);
    sq += __shfl_xor(sq, 32);
    __shared__ float rs[4][32], rq[4][32];
    int wave = threadIdx.x >> 6;
    if ((lane >> 5) == 0) { rs[wave][c] = sm; rq[wave][c] = sq; }
    __syncthreads();
    if (threadIdx.x < 32) {
        int cc = threadIdx.x;
        atomicAdd(&stats[cc], rs[0][cc] + rs[1][cc] + rs[2][cc] + rs[3][cc]);
        atomicAdd(&stats[32 + cc], rq[0][cc] + rq[1][cc] + rq[2][cc] + rq[3][cc]);
    }
}

// Fold level stats + SharedConv scale + BN into per-(level,channel) affine:
// branch value = leaky(d*A + B).
__global__ void fin3_kernel(const float* __restrict__ lstats, const float* __restrict__ kw,
                            const float* __restrict__ gw, const float* __restrict__ bw,
                            const float* __restrict__ kh, const float* __restrict__ gh,
                            const float* __restrict__ bh, float* __restrict__ lp) {
    int t = threadIdx.x;
    if (t >= 192) return;
    int l = t >> 5, c = t & 31;
    float mz = lstats[l * 64 + c] / NPIXF;
    float vz = lstats[l * 64 + 32 + c] / NPIXF - mz * mz;
    float kwc = kw[c];
    float aw = gw[c] * rsqrtf(kwc * kwc * vz + 1e-5f);
    float khc = kh[c];
    float ah = gh[c] * rsqrtf(khc * khc * vz + 1e-5f);
    float* o = lp + (size_t)(l * 32 + c) * 4;
    o[0] = kwc * aw;
    o[1] = bw[c] - kwc * mz * aw;
    o[2] = khc * ah;
    o[3] = bh[c] - khc * mz * ah;
}

// Final: 4 consecutive w-px per thread, float4 stores of both branch channels.
__global__ __launch_bounds__(256) void final_kernel(const float* __restrict__ d1,
                                                    const float* __restrict__ d2,
                                                    const float* __restrict__ d3,
                                                    const float* __restrict__ d4,
                                                    const float* __restrict__ d5,
                                                    const float* __restrict__ d6,
                                                    const float* __restrict__ lp,
                                                    float* __restrict__ out) {
    int idx = blockIdx.x * 256 + threadIdx.x;   // 8,388,608 threads
    int w4 = (idx & 127) << 2;
    int h = (idx >> 7) & 511;
    int c = (idx >> 16) & 31;
    int b = idx >> 21;
    const float* ds[6] = {d1, d2, d3, d4, d5, d6};
    const int ss[6] = {171, 57, 19, 7, 3, 1};
    float accw[4] = {0.f, 0.f, 0.f, 0.f};
    float acch[4] = {0.f, 0.f, 0.f, 0.f};
    #pragma unroll
    for (int l = 0; l < 6; ++l) {
        int s = ss[l];
        int sh = (h * s) >> 9;
        const float* base = ds[l] + ((size_t)(b * 32 + c) * s + sh) * s;
        const float* a = lp + (size_t)(l * 32 + c) * 4;
        float a0 = a[0], a1 = a[1], a2 = a[2], a3 = a[3];
        #pragma unroll
        for (int k = 0; k < 4; ++k) {
            int sw = ((w4 + k) * s) >> 9;
            float val = base[sw];
            accw[k] += leaky(val * a0 + a1);
            acch[k] += leaky(val * a2 + a3);
        }
    }
    size_t o = (((size_t)(b * 64 + c)) << 18) + ((size_t)h << 9) + w4;
    *(float4*)(out + o) = make_float4(accw[0], accw[1], accw[2], accw[3]);
    *(float4*)(out + o + (((size_t)32) << 18)) = make_float4(acch[0], acch[1], acch[2], acch[3]);
}

extern "C" void kernel_launch(void* const* d_in, const int* in_sizes, int n_in,
                              void* d_out, int out_size, void* d_ws, size_t ws_size,
                              hipStream_t stream) {
    const float* x     = (const float*)d_in[0];
    const float* w1    = (const float*)d_in[1];
    const float* b1    = (const float*)d_in[2];
    const float* w2    = (const float*)d_in[3];
    const float* b2    = (const float*)d_in[4];
    const float* bn1g  = (const float*)d_in[5];
    const float* bn1b  = (const float*)d_in[6];
    const float* w3    = (const float*)d_in[7];
    const float* b3    = (const float*)d_in[8];
    const float* bn2g  = (const float*)d_in[9];
    const float* bn2b  = (const float*)d_in[10];
    const float* kd    = (const float*)d_in[11];
    const float* kw    = (const float*)d_in[12];
    const float* bnwg  = (const float*)d_in[13];
    const float* bnwb  = (const float*)d_in[14];
    const float* kh    = (const float*)d_in[15];
    const float* bnhg  = (const float*)d_in[16];
    const float* bnhb  = (const float*)d_in[17];
    float* out = (float*)d_out;

    char* ws = (char*)d_ws;
    unsigned char* modeq = (unsigned char*)ws;            // 3,145,728 B
    float* stats1 = (float*)(ws + 3145728);               // 64 f
    float* stats2 = stats1 + 64;                          // 64 f
    float* lstats = stats2 + 64;                          // 384 f
    float* p1 = (float*)(ws + 3145728 + 2048);            // 64 f
    float* p2 = p1 + 64;                                  // 64 f
    float* lp = p2 + 64;                                  // 768 f
    float* d1 = (float*)(ws + 3151360);                   // 3,742,848 f
    float* d2 = d1 + 3742848;                             // 415,872 f
    float* d3 = d2 + 415872;                              // 46,208 f
    float* d4 = d3 + 46208;                               // 6,272 f
    float* d5 = d4 + 6272;                                // 1,152 f
    float* d6 = d5 + 1152;                                // 128 f

    hipMemsetAsync(stats1, 0, 2048, stream);   // stats1+stats2+lstats contiguous

    mode_kernel<<<dim3(2, 64, 12), 256, 0, stream>>>(x, modeq);
    stats_kernel<<<1024, 256, 0, stream>>>(modeq, w1, b1, w2, b2, nullptr, 0, stats1);
    fin1_kernel<<<1, 32, 0, stream>>>(stats1, bn1g, bn1b, p1);
    stats_kernel<<<1024, 256, 0, stream>>>(modeq, w1, b1, w2, b2, p1, 1, stats2);
    fin2_kernel<<<1, 32, 0, stream>>>(stats2, w3, b3, bn2g, bn2b, p2);

    d1_kernel<<<dim3(3, 171, 4), 64, 0, stream>>>(modeq, w1, b1, w2, b2, w3, b3, p1, p2, kd, d1);
    down_kernel<<<(415872 + 255) / 256, 256, 0, stream>>>(d1, d2, kd, 171, 57, 415872);
    down_kernel<<<(46208 + 255) / 256, 256, 0, stream>>>(d2, d3, kd, 57, 19, 46208);
    down_kernel<<<(6272 + 255) / 256, 256, 0, stream>>>(d3, d4, kd, 19, 7, 6272);
    down_kernel<<<(1152 + 255) / 256, 256, 0, stream>>>(d4, d5, kd, 7, 3, 1152);
    down_kernel<<<1, 256, 0, stream>>>(d5, d6, kd, 3, 1, 128);

    lstats_kernel<<<128, 256, 0, stream>>>(d1, 171, lstats + 0 * 64);
    lstats_kernel<<<16, 256, 0, stream>>>(d2, 57, lstats + 1 * 64);
    lstats_kernel<<<2, 256, 0, stream>>>(d3, 19, lstats + 2 * 64);
    lstats_kernel<<<1, 256, 0, stream>>>(d4, 7, lstats + 3 * 64);
    lstats_kernel<<<1, 256, 0, stream>>>(d5, 3, lstats + 4 * 64);
    lstats_kernel<<<1, 256, 0, stream>>>(d6, 1, lstats + 5 * 64);
    fin3_kernel<<<1, 192, 0, stream>>>(lstats, kw, bnwg, bnwb, kh, bnhg, bnhb, lp);

    final_kernel<<<32768, 256, 0, stream>>>(d1, d2, d3, d4, d5, d6, lp, out);
}

// Round 3
// 546.731 us; speedup vs baseline: 1.6944x; 1.2482x over previous
//
#include <hip/hip_runtime.h>

#define HH 512
#define WW 512
#define HW 262144          // 512*512
#define NPIX 1048576       // 4*512*512
#define NPIXF 1048576.0f

typedef float f4 __attribute__((ext_vector_type(4)));

__device__ __forceinline__ float leaky(float v) { return v > 0.f ? v : 0.01f * v; }

// replication count of source index i at level size s (nearest upsample to 512)
__device__ __forceinline__ float repw(int i, int s) {
    return (float)(((i + 1) * 512 + s - 1) / s - (i * 512 + s - 1) / s);
}

__device__ __forceinline__ void hins(unsigned long long& h0, unsigned long long& h1,
                                     unsigned& c16, int val) {
    unsigned long long inc = 1ull << ((val & 7) * 8);
    h0 += (val < 8) ? inc : 0;
    h1 += (val >= 8 && val < 16) ? inc : 0;
    c16 += (unsigned)(val >> 4);
}
__device__ __forceinline__ void hrem(unsigned long long& h0, unsigned long long& h1,
                                     unsigned& c16, int val) {
    unsigned long long inc = 1ull << ((val & 7) * 8);
    h0 -= (val < 8) ? inc : 0;
    h1 -= (val >= 8 && val < 16) ? inc : 0;
    c16 -= (unsigned)(val >> 4);
}

// ---------------------------------------------------------------------------
// Mode pooling: shared column histograms (v2, unchanged from round 2).
// ---------------------------------------------------------------------------
__global__ __launch_bounds__(256) void mode_kernel(const float* __restrict__ x,
                                                   unsigned char* __restrict__ modeq) {
    __shared__ unsigned char q[18 * 272];
    __shared__ unsigned ch[267 * 5];
    const int plane = blockIdx.z;
    const int tc0 = blockIdx.x * 256;
    const int tr0 = blockIdx.y * 8;
    const float* xp = x + (size_t)plane * HW;
    for (int idx = threadIdx.x; idx < 18 * 266; idx += 256) {
        int r = idx / 266;
        int cc = idx - r * 266;
        int gr = tr0 + r - 5; gr = gr < 0 ? -gr : (gr > 511 ? 1022 - gr : gr);
        int gc = tc0 + cc - 5; gc = gc < 0 ? -gc : (gc > 511 ? 1022 - gc : gc);
        float v = rintf(xp[gr * WW + gc] * 15.9375f);
        v = fminf(fmaxf(v, 0.f), 16.f);
        q[r * 272 + cc] = (unsigned char)(int)v;
    }
    const int t = threadIdx.x;
    unsigned long long A0 = 0, A1 = 0; unsigned A2 = 0;
    unsigned long long B0 = 0, B1 = 0; unsigned B2 = 0;
    __syncthreads();
    for (int r = 0; r < 8; ++r) {
        if (r == 0) {
            #pragma unroll
            for (int v = 0; v < 11; ++v) {
                hins(A0, A1, A2, q[v * 272 + t]);
                if (t < 10) hins(B0, B1, B2, q[v * 272 + 256 + t]);
            }
        } else {
            hrem(A0, A1, A2, q[(r - 1) * 272 + t]);
            hins(A0, A1, A2, q[(r + 10) * 272 + t]);
            if (t < 10) {
                hrem(B0, B1, B2, q[(r - 1) * 272 + 256 + t]);
                hins(B0, B1, B2, q[(r + 10) * 272 + 256 + t]);
            }
        }
        __syncthreads();
        ch[t * 5 + 0] = (unsigned)A0;
        ch[t * 5 + 1] = (unsigned)(A0 >> 32);
        ch[t * 5 + 2] = (unsigned)A1;
        ch[t * 5 + 3] = (unsigned)(A1 >> 32);
        ch[t * 5 + 4] = A2;
        if (t < 10) {
            ch[(256 + t) * 5 + 0] = (unsigned)B0;
            ch[(256 + t) * 5 + 1] = (unsigned)(B0 >> 32);
            ch[(256 + t) * 5 + 2] = (unsigned)B1;
            ch[(256 + t) * 5 + 3] = (unsigned)(B1 >> 32);
            ch[(256 + t) * 5 + 4] = B2;
        }
        __syncthreads();
        unsigned long long H0 = 0, H1 = 0; unsigned C = 0;
        #pragma unroll
        for (int v = 0; v < 11; ++v) {
            const unsigned* p = &ch[(t + v) * 5];
            H0 += (unsigned long long)p[0] | ((unsigned long long)p[1] << 32);
            H1 += (unsigned long long)p[2] | ((unsigned long long)p[3] << 32);
            C += p[4];
        }
        unsigned m = 0;
        #pragma unroll
        for (int i = 0; i < 8; ++i) {
            unsigned cnt = (unsigned)(H0 >> (8 * i)) & 0xFFu;
            unsigned val = (cnt << 8) | (unsigned)(16 - i);
            m = m > val ? m : val;
        }
        #pragma unroll
        for (int i = 8; i < 16; ++i) {
            unsigned cnt = (unsigned)(H1 >> (8 * (i - 8))) & 0xFFu;
            unsigned val = (cnt << 8) | (unsigned)(16 - i);
            m = m > val ? m : val;
        }
        unsigned val16 = (C << 8);
        m = m > val16 ? m : val16;
        int k = 16 - (int)(m & 0xFFu);
        modeq[(size_t)plane * HW + (size_t)(tr0 + r) * WW + tc0 + t] = (unsigned char)k;
    }
}

// ---------------------------------------------------------------------------
// Joint histogram of (k0,k1,k2) triples, 17^3=4913 bins.
// 128 blocks x 8192 px; per-block LDS hist flushed to disjoint partials.
// ---------------------------------------------------------------------------
__global__ __launch_bounds__(256) void hist_kernel(const unsigned char* __restrict__ modeq,
                                                   unsigned* __restrict__ partial) {
    __shared__ unsigned lh[4913];
    for (int i = threadIdx.x; i < 4913; i += 256) lh[i] = 0;
    __syncthreads();
    int base = blockIdx.x * 8192;
    int b = base >> 18;
    int hw0 = base & (HW - 1);
    const unsigned char* mp = modeq + (size_t)b * 3 * HW;
    #pragma unroll
    for (int j = 0; j < 8; ++j) {
        int g = threadIdx.x + 256 * j;
        int hw = hw0 + g * 4;
        unsigned u0 = *(const unsigned*)(mp + hw);
        unsigned u1 = *(const unsigned*)(mp + hw + HW);
        unsigned u2 = *(const unsigned*)(mp + hw + 2 * HW);
        #pragma unroll
        for (int k = 0; k < 4; ++k) {
            int k0 = (u0 >> (8 * k)) & 0xFF;
            int k1 = (u1 >> (8 * k)) & 0xFF;
            int k2 = (u2 >> (8 * k)) & 0xFF;
            atomicAdd(&lh[k0 + 17 * k1 + 289 * k2], 1u);
        }
    }
    __syncthreads();
    unsigned* pp = partial + blockIdx.x * 4913;
    for (int i = threadIdx.x; i < 4913; i += 256) pp[i] = lh[i];
}

// ---------------------------------------------------------------------------
// Single-block BN solve: reduce partial hists; BN1 stats via t1 moments
// (6 first + 21 second, channel-independent); fin1; BN2 stats via bin sweep;
// fin2. Writes p1, p2.
// ---------------------------------------------------------------------------
__global__ __launch_bounds__(1024) void solve_kernel(const unsigned* __restrict__ partial,
                                                     const float* __restrict__ w1,
                                                     const float* __restrict__ b1,
                                                     const float* __restrict__ w2,
                                                     const float* __restrict__ b2,
                                                     const float* __restrict__ g1,
                                                     const float* __restrict__ bb1,
                                                     const float* __restrict__ w3,
                                                     const float* __restrict__ b3,
                                                     const float* __restrict__ g2,
                                                     const float* __restrict__ bb2,
                                                     float* __restrict__ p1,
                                                     float* __restrict__ p2) {
    __shared__ float hist[4913];
    __shared__ float redu[27 * 16];
    __shared__ float a1s[32], c1s[32];
    __shared__ float rsm[1024], rsq[1024];
    const int tid = threadIdx.x;
    // phase 0: sum partial hists
    for (int bin = tid; bin < 4913; bin += 1024) {
        unsigned s = 0;
        for (int blk = 0; blk < 128; ++blk) s += partial[blk * 4913 + bin];
        hist[bin] = (float)s;
    }
    float w1r[18], b1r[6];
    #pragma unroll
    for (int k = 0; k < 18; ++k) w1r[k] = w1[k];
    #pragma unroll
    for (int o = 0; o < 6; ++o) b1r[o] = b1[o];
    __syncthreads();
    // phase A: t1 moments
    float M[27];
    #pragma unroll
    for (int i = 0; i < 27; ++i) M[i] = 0.f;
    for (int bin = tid; bin < 4913; bin += 1024) {
        float cnt = hist[bin];
        int k0 = bin % 17;
        int r = bin / 17;
        int k1 = r % 17;
        int k2 = r / 17;
        float xm0 = k0 * 0.0625f, xm1 = k1 * 0.0625f, xm2 = k2 * 0.0625f;
        float t1[6];
        #pragma unroll
        for (int o = 0; o < 6; ++o)
            t1[o] = leaky(xm0 * w1r[o * 3] + xm1 * w1r[o * 3 + 1] + xm2 * w1r[o * 3 + 2] + b1r[o]);
        #pragma unroll
        for (int o = 0; o < 6; ++o) M[o] += cnt * t1[o];
        int ii = 6;
        #pragma unroll
        for (int j = 0; j < 6; ++j)
            #pragma unroll
            for (int k = j; k < 6; ++k) { M[ii] += cnt * t1[j] * t1[k]; ++ii; }
    }
    #pragma unroll
    for (int i = 0; i < 27; ++i) {
        float v = M[i];
        #pragma unroll
        for (int off = 32; off >= 1; off >>= 1) v += __shfl_xor(v, off);
        if ((tid & 63) == 0) redu[i * 16 + (tid >> 6)] = v;
    }
    __syncthreads();
    if (tid < 27) {
        float s = 0.f;
        #pragma unroll
        for (int w = 0; w < 16; ++w) s += redu[tid * 16 + w];
        redu[tid * 16] = s;
    }
    __syncthreads();
    if (tid < 32) {
        int c = tid;
        float w2r[6];
        #pragma unroll
        for (int k = 0; k < 6; ++k) w2r[k] = w2[c * 6 + k];
        float b2c = b2[c];
        float wm1 = 0.f;
        #pragma unroll
        for (int k = 0; k < 6; ++k) wm1 += w2r[k] * redu[k * 16];
        float q = 0.f;
        int ii = 6;
        #pragma unroll
        for (int j = 0; j < 6; ++j)
            #pragma unroll
            for (int k = j; k < 6; ++k) {
                float f = w2r[j] * w2r[k] * redu[ii * 16];
                q += (j == k) ? f : 2.f * f;
                ++ii;
            }
        float mean = b2c + wm1 / NPIXF;
        float ex2 = b2c * b2c + 2.f * b2c * (wm1 / NPIXF) + q / NPIXF;
        float var = ex2 - mean * mean;
        float a = g1[c] * rsqrtf(var + 1e-5f);
        float cc = bb1[c] - mean * a;
        a1s[c] = a; c1s[c] = cc;
        p1[c] = a; p1[32 + c] = cc;
    }
    __syncthreads();
    // phase B: per-(bin,channel) stats of t = leaky(bn1(h2))
    int c = tid & 31;
    int grp = tid >> 5;   // 0..31
    float w2r[6];
    #pragma unroll
    for (int k = 0; k < 6; ++k) w2r[k] = w2[c * 6 + k];
    float b2c = b2[c];
    float a1 = a1s[c], c1 = c1s[c];
    float sm = 0.f, sq = 0.f;
    for (int bin = grp; bin < 4913; bin += 32) {
        float cnt = hist[bin];
        int k0 = bin % 17;
        int r = bin / 17;
        int k1 = r % 17;
        int k2 = r / 17;
        float xm0 = k0 * 0.0625f, xm1 = k1 * 0.0625f, xm2 = k2 * 0.0625f;
        float t1[6];
        #pragma unroll
        for (int o = 0; o < 6; ++o)
            t1[o] = leaky(xm0 * w1r[o * 3] + xm1 * w1r[o * 3 + 1] + xm2 * w1r[o * 3 + 2] + b1r[o]);
        float h2 = b2c;
        #pragma unroll
        for (int k = 0; k < 6; ++k) h2 += w2r[k] * t1[k];
        float t = leaky(a1 * h2 + c1);
        sm += cnt * t;
        sq += cnt * t * t;
    }
    rsm[tid] = sm; rsq[tid] = sq;
    __syncthreads();
    if (tid < 32) {
        float s = 0.f, qq = 0.f;
        #pragma unroll
        for (int g = 0; g < 32; ++g) { s += rsm[g * 32 + tid]; qq += rsq[g * 32 + tid]; }
        float mt = s / NPIXF;
        float vt = qq / NPIXF - mt * mt;
        float m2 = w3[tid] * mt + b3[tid];
        float v2 = w3[tid] * w3[tid] * vt;
        float a = g2[tid] * rsqrtf(v2 + 1e-5f);
        p2[tid] = a;
        p2[32 + tid] = bb2[tid] - m2 * a;
    }
}

// ---------------------------------------------------------------------------
// Level-1 downsample fused with the prepare chain (unchanged).
// ---------------------------------------------------------------------------
__global__ __launch_bounds__(64) void d1_kernel(const unsigned char* __restrict__ modeq,
                                                const float* __restrict__ w1,
                                                const float* __restrict__ b1,
                                                const float* __restrict__ w2,
                                                const float* __restrict__ b2,
                                                const float* __restrict__ w3,
                                                const float* __restrict__ b3,
                                                const float* __restrict__ p1,
                                                const float* __restrict__ p2,
                                                const float* __restrict__ kd,
                                                float* __restrict__ d1) {
    int j = blockIdx.x * 64 + threadIdx.x;
    if (j >= 171) return;
    int i = blockIdx.y;
    int b = blockIdx.z;
    float acc[32];
    #pragma unroll
    for (int c = 0; c < 32; ++c) acc[c] = 0.f;
    const unsigned char* mp = modeq + (size_t)b * 3 * HW;
    #pragma unroll
    for (int u = 0; u < 3; ++u) {
        int r = 3 * i - 1 + u;
        if (r < 0 || r > 511) continue;
        #pragma unroll
        for (int v = 0; v < 3; ++v) {
            int col = 3 * j - 1 + v;
            if (col < 0 || col > 511) continue;
            int off = r * WW + col;
            float xm0 = mp[off] * 0.0625f, xm1 = mp[off + HW] * 0.0625f, xm2 = mp[off + 2 * HW] * 0.0625f;
            float t1[6];
            #pragma unroll
            for (int o = 0; o < 6; ++o)
                t1[o] = leaky(xm0 * w1[o * 3] + xm1 * w1[o * 3 + 1] + xm2 * w1[o * 3 + 2] + b1[o]);
            #pragma unroll
            for (int c = 0; c < 32; ++c) {
                float h2 = b2[c];
                #pragma unroll
                for (int k = 0; k < 6; ++k) h2 += w2[c * 6 + k] * t1[k];
                float t = leaky(h2 * p1[c] + p1[32 + c]);
                float uu = t * w3[c] + b3[c];
                float hv = leaky(uu * p2[c] + p2[32 + c]);
                acc[c] += hv * kd[c * 9 + u * 3 + v];
            }
        }
    }
    size_t base = ((size_t)(b * 32) * 171 + i) * 171 + j;
    #pragma unroll
    for (int c = 0; c < 32; ++c) d1[base + (size_t)c * 29241] = acc[c];
}

// ---------------------------------------------------------------------------
// Fused pyramid tail: block = (b,c) plane. Computes d2..d6 through LDS and
// all six weighted level stats (atomicAdd into lstats, zeroed by memset).
// ---------------------------------------------------------------------------
__device__ __forceinline__ void red_atomic(float sm, float sq, float* rsc,
                                           float* lst, int c) {
    #pragma unroll
    for (int off = 32; off >= 1; off >>= 1) {
        sm += __shfl_xor(sm, off);
        sq += __shfl_xor(sq, off);
    }
    __syncthreads();
    int wv = threadIdx.x >> 6;
    if ((threadIdx.x & 63) == 0) { rsc[wv] = sm; rsc[8 + wv] = sq; }
    __syncthreads();
    if (threadIdx.x == 0) {
        atomicAdd(&lst[c], rsc[0] + rsc[1] + rsc[2] + rsc[3]);
        atomicAdd(&lst[32 + c], rsc[8] + rsc[9] + rsc[10] + rsc[11]);
    }
}

__device__ __forceinline__ void lvl(const float* src, int sin, float* dstL,
                                    float* dstG, int sout, const float* kreg,
                                    float* rsc, float* lst, int c) {
    float sm = 0.f, sq = 0.f;
    int n = sout * sout;
    for (int i = threadIdx.x; i < n; i += 256) {
        int oi = i / sout, oj = i - oi * sout;
        float acc = 0.f;
        #pragma unroll
        for (int u = 0; u < 3; ++u) {
            int r = 3 * oi - 1 + u;
            if ((unsigned)r >= (unsigned)sin) continue;
            #pragma unroll
            for (int v = 0; v < 3; ++v) {
                int cc = 3 * oj - 1 + v;
                if ((unsigned)cc >= (unsigned)sin) continue;
                acc += src[r * sin + cc] * kreg[u * 3 + v];
            }
        }
        dstG[i] = acc;
        if (dstL) dstL[i] = acc;
        float w = repw(oi, sout) * repw(oj, sout);
        sm += w * acc;
        sq += w * acc * acc;
    }
    red_atomic(sm, sq, rsc, lst, c);
}

__global__ __launch_bounds__(256) void pyramid_kernel(const float* __restrict__ d1,
                                                      float* __restrict__ d2,
                                                      float* __restrict__ d3,
                                                      float* __restrict__ d4,
                                                      float* __restrict__ d5,
                                                      float* __restrict__ d6,
                                                      const float* __restrict__ kd,
                                                      float* __restrict__ lstats) {
    __shared__ float buf2[3249];
    __shared__ float buf3[361];
    __shared__ float buf4[49];
    __shared__ float buf5[9];
    __shared__ float rsc[16];
    int bc = blockIdx.x;
    int c = bc & 31;
    float kreg[9];
    #pragma unroll
    for (int qq = 0; qq < 9; ++qq) kreg[qq] = kd[c * 9 + qq];
    const float* s1 = d1 + (size_t)bc * 29241;
    // level-1 stats
    float sm = 0.f, sq = 0.f;
    for (int i = threadIdx.x; i < 29241; i += 256) {
        int oi = i / 171, oj = i - oi * 171;
        float w = repw(oi, 171) * repw(oj, 171);
        float v = s1[i];
        sm += w * v;
        sq += w * v * v;
    }
    red_atomic(sm, sq, rsc, &lstats[0 * 64], c);
    lvl(s1, 171, buf2, d2 + (size_t)bc * 3249, 57, kreg, rsc, &lstats[1 * 64], c);
    lvl(buf2, 57, buf3, d3 + (size_t)bc * 361, 19, kreg, rsc, &lstats[2 * 64], c);
    lvl(buf3, 19, buf4, d4 + (size_t)bc * 49, 7, kreg, rsc, &lstats[3 * 64], c);
    lvl(buf4, 7, buf5, d5 + (size_t)bc * 9, 3, kreg, rsc, &lstats[4 * 64], c);
    lvl(buf5, 3, nullptr, d6 + bc, 1, kreg, rsc, &lstats[5 * 64], c);
}

// Fold level stats + SharedConv scale + BN into per-(level,channel) affine.
__global__ void fin3_kernel(const float* __restrict__ lstats, const float* __restrict__ kw,
                            const float* __restrict__ gw, const float* __restrict__ bw,
                            const float* __restrict__ kh, const float* __restrict__ gh,
                            const float* __restrict__ bh, float* __restrict__ lp) {
    int t = threadIdx.x;
    if (t >= 192) return;
    int l = t >> 5, c = t & 31;
    float mz = lstats[l * 64 + c] / NPIXF;
    float vz = lstats[l * 64 + 32 + c] / NPIXF - mz * mz;
    float kwc = kw[c];
    float aw = gw[c] * rsqrtf(kwc * kwc * vz + 1e-5f);
    float khc = kh[c];
    float ah = gh[c] * rsqrtf(khc * khc * vz + 1e-5f);
    float* o = lp + (size_t)(l * 32 + c) * 4;
    o[0] = kwc * aw;
    o[1] = bw[c] - kwc * mz * aw;
    o[2] = khc * ah;
    o[3] = bh[c] - khc * mz * ah;
}

// Final: 4 consecutive w-px per thread, nontemporal float4 stores.
__global__ __launch_bounds__(256) void final_kernel(const float* __restrict__ d1,
                                                    const float* __restrict__ d2,
                                                    const float* __restrict__ d3,
                                                    const float* __restrict__ d4,
                                                    const float* __restrict__ d5,
                                                    const float* __restrict__ d6,
                                                    const float* __restrict__ lp,
                                                    float* __restrict__ out) {
    int idx = blockIdx.x * 256 + threadIdx.x;
    int w4 = (idx & 127) << 2;
    int h = (idx >> 7) & 511;
    int c = (idx >> 16) & 31;
    int b = idx >> 21;
    const float* ds[6] = {d1, d2, d3, d4, d5, d6};
    const int ss[6] = {171, 57, 19, 7, 3, 1};
    float accw[4] = {0.f, 0.f, 0.f, 0.f};
    float acch[4] = {0.f, 0.f, 0.f, 0.f};
    #pragma unroll
    for (int l = 0; l < 6; ++l) {
        int s = ss[l];
        int sh = (h * s) >> 9;
        const float* base = ds[l] + ((size_t)(b * 32 + c) * s + sh) * s;
        const float* a = lp + (size_t)(l * 32 + c) * 4;
        float a0 = a[0], a1 = a[1], a2 = a[2], a3 = a[3];
        #pragma unroll
        for (int k = 0; k < 4; ++k) {
            int sw = ((w4 + k) * s) >> 9;
            float val = base[sw];
            accw[k] += leaky(val * a0 + a1);
            acch[k] += leaky(val * a2 + a3);
        }
    }
    size_t o = (((size_t)(b * 64 + c)) << 18) + ((size_t)h << 9) + w4;
    f4 vw = {accw[0], accw[1], accw[2], accw[3]};
    f4 vh = {acch[0], acch[1], acch[2], acch[3]};
    __builtin_nontemporal_store(vw, (f4*)(out + o));
    __builtin_nontemporal_store(vh, (f4*)(out + o + (((size_t)32) << 18)));
}

extern "C" void kernel_launch(void* const* d_in, const int* in_sizes, int n_in,
                              void* d_out, int out_size, void* d_ws, size_t ws_size,
                              hipStream_t stream) {
    const float* x     = (const float*)d_in[0];
    const float* w1    = (const float*)d_in[1];
    const float* b1    = (const float*)d_in[2];
    const float* w2    = (const float*)d_in[3];
    const float* b2    = (const float*)d_in[4];
    const float* bn1g  = (const float*)d_in[5];
    const float* bn1b  = (const float*)d_in[6];
    const float* w3    = (const float*)d_in[7];
    const float* b3    = (const float*)d_in[8];
    const float* bn2g  = (const float*)d_in[9];
    const float* bn2b  = (const float*)d_in[10];
    const float* kd    = (const float*)d_in[11];
    const float* kw    = (const float*)d_in[12];
    const float* bnwg  = (const float*)d_in[13];
    const float* bnwb  = (const float*)d_in[14];
    const float* kh    = (const float*)d_in[15];
    const float* bnhg  = (const float*)d_in[16];
    const float* bnhb  = (const float*)d_in[17];
    float* out = (float*)d_out;

    char* ws = (char*)d_ws;
    unsigned char* modeq = (unsigned char*)ws;                 // 3,145,728 B
    float* lstats = (float*)(ws + 3145728);                    // 384 f (memset zone 2048 B)
    float* p1 = (float*)(ws + 3145728 + 2048);                 // 64 f
    float* p2 = p1 + 64;                                       // 64 f
    float* lp = p2 + 64;                                       // 768 f  (ends at 3,151,360)
    unsigned* partial = (unsigned*)(ws + 3151360);             // 128*4913 u32 = 2,515,456 B
    float* d1 = (float*)(ws + 3151360 + 2515456);              // 3,742,848 f
    float* d2 = d1 + 3742848;                                  // 415,872 f
    float* d3 = d2 + 415872;                                   // 46,208 f
    float* d4 = d3 + 46208;                                    // 6,272 f
    float* d5 = d4 + 6272;                                     // 1,152 f
    float* d6 = d5 + 1152;                                     // 128 f

    hipMemsetAsync(lstats, 0, 2048, stream);

    mode_kernel<<<dim3(2, 64, 12), 256, 0, stream>>>(x, modeq);
    hist_kernel<<<128, 256, 0, stream>>>(modeq, partial);
    solve_kernel<<<1, 1024, 0, stream>>>(partial, w1, b1, w2, b2, bn1g, bn1b,
                                         w3, b3, bn2g, bn2b, p1, p2);
    d1_kernel<<<dim3(3, 171, 4), 64, 0, stream>>>(modeq, w1, b1, w2, b2, w3, b3, p1, p2, kd, d1);
    pyramid_kernel<<<128, 256, 0, stream>>>(d1, d2, d3, d4, d5, d6, kd, lstats);
    fin3_kernel<<<1, 192, 0, stream>>>(lstats, kw, bnwg, bnwb, kh, bnhg, bnhb, lp);
    final_kernel<<<32768, 256, 0, stream>>>(d1, d2, d3, d4, d5, d6, lp, out);
}